// Round 2
// 1182.368 us; speedup vs baseline: 1.1936x; 1.1936x over previous
//
#include <hip/hip_runtime.h>
#include <math.h>
#include <stdint.h>

#define KDIM 512
#define HEADS 8
#define NBLK 4
#define TSEQ 512
#define BATCH_ 4
#define ROWS 2048
#define DMODEL 4096
#define VOCAB_ 32000
#define FFDIM 2048

typedef __attribute__((ext_vector_type(4))) float f32x4;
typedef __attribute__((ext_vector_type(8))) short s16x8;
typedef unsigned short u16t;

// fp32 -> bf16 round-to-nearest-even
__device__ __forceinline__ u16t f2bf(float f) {
    union { float f; unsigned u; } cv; cv.f = f;
    return (u16t)((cv.u + 0x7FFFu + ((cv.u >> 16) & 1u)) >> 16);
}

// async 16B global -> LDS (wave-uniform LDS base + lane*16). CK-style casts.
__device__ __forceinline__ void gload_lds16(const void* g, void* lds) {
    __builtin_amdgcn_global_load_lds(
        (const __attribute__((address_space(1))) unsigned int*)(uintptr_t)g,
        (__attribute__((address_space(3))) unsigned int*)(unsigned int)(uintptr_t)lds,
        16, 0, 0);
}

// ---------------------------------------------------------------------------
// bf16 MFMA GEMM, TRANSB form: C[m][n] = scale * sum_k A[m][k] * Bt[n][k]
// A: [M x K] bf16 row-major (lda), Bt: [N x K] bf16 row-major (ldb).
// BM x BN tile, 256 threads = 4 waves (2x2), each wave BM/2 x BN/2 via
// 16x16x32 MFMAs. BK=64: one barrier-pair covers two 32-k MFMA groups
// (halves the vmcnt-drain stalls vs BK=32). LDS staged via
// global_load_lds(16B) with a full 3-bit XOR swizzle on the 16B k-chunk:
// phys = kc ^ (row & 7). Fragment ds_read_b128 is then exactly 2-way
// bank-aliased across the wave (free on CDNA4, m136).
// Batched over blockIdx.z with (zb, zh) two-level strides; split-K is
// expressed through the same strides (aSB/bSB = k-chunk offset, cSB =
// partial-output offset, Hn=1).
// MASK = causal tile skip: tiles entirely above the diagonal return
// without writing anything; in-tile masking is done by the softmax.
// ---------------------------------------------------------------------------
template<int BM, int BN, bool OUTBF, bool BIAS, bool GELU, bool MASK, bool KTRI>
__global__ __launch_bounds__(256, 2) void gemm_bf16(
    const u16t* __restrict__ A, const u16t* __restrict__ Bt,
    const float* __restrict__ bias, void* __restrict__ Cv,
    int Kd, int lda, int ldb, int ldc,
    long long aSB, long long aSH, long long bSB, long long bSH,
    long long cSB, long long cSH, int Hn, float scale)
{
    const int m0 = blockIdx.y * BM, n0 = blockIdx.x * BN;
    if (MASK && n0 > m0) return;      // fully-masked tile: softmax handles it

    const int zb = blockIdx.z / Hn, zh = blockIdx.z % Hn;
    A  += zb * aSB + zh * aSH;
    Bt += zb * bSB + zh * bSH;
    const int tid = threadIdx.x;
    const int wave = tid >> 6, lane = tid & 63;
    const int quad = lane >> 4, l15 = lane & 15;
    const int wm = (wave >> 1) * (BM / 2), wn = (wave & 1) * (BN / 2);
    constexpr int MT = BM / 32, NT = BN / 32;

    __shared__ __align__(16) u16t As[BM * 64];
    __shared__ __align__(16) u16t Bs[BN * 64];

    f32x4 acc[MT][NT];
    #pragma unroll
    for (int i = 0; i < MT; i++)
        #pragma unroll
        for (int j = 0; j < NT; j++)
            acc[i][j] = (f32x4){0.f, 0.f, 0.f, 0.f};

    const int kend = KTRI ? (Kd < m0 + BM ? Kd : m0 + BM) : Kd;

    for (int k0 = 0; k0 < kend; k0 += 64) {
        #pragma unroll
        for (int r = 0; r < BM / 32; ++r) {
            int cc = r * 256 + tid;
            int row = cc >> 3, pc = cc & 7;          // 8 x 16B chunks per row
            int kc = pc ^ (row & 7);                 // involution swizzle
            gload_lds16(A + (long long)(m0 + row) * lda + k0 + kc * 8, &As[cc * 8]);
        }
        #pragma unroll
        for (int r = 0; r < BN / 32; ++r) {
            int cc = r * 256 + tid;
            int row = cc >> 3, pc = cc & 7;
            int kc = pc ^ (row & 7);
            gload_lds16(Bt + (long long)(n0 + row) * ldb + k0 + kc * 8, &Bs[cc * 8]);
        }
        __syncthreads();   // drains vmcnt for the LDS DMA

        #pragma unroll
        for (int g = 0; g < 2; ++g) {                // two 32-k MFMA groups
            s16x8 af[MT], bfr[NT];
            #pragma unroll
            for (int i = 0; i < MT; i++) {
                int row = wm + i * 16 + l15;
                int pc = (g * 4 + quad) ^ (row & 7);
                af[i] = *(const s16x8*)&As[row * 64 + pc * 8];
            }
            #pragma unroll
            for (int j = 0; j < NT; j++) {
                int row = wn + j * 16 + l15;
                int pc = (g * 4 + quad) ^ (row & 7);
                bfr[j] = *(const s16x8*)&Bs[row * 64 + pc * 8];
            }
            #pragma unroll
            for (int i = 0; i < MT; i++)
                #pragma unroll
                for (int j = 0; j < NT; j++)
                    acc[i][j] = __builtin_amdgcn_mfma_f32_16x16x32_bf16(
                        af[i], bfr[j], acc[i][j], 0, 0, 0);
        }
        __syncthreads();
    }

    // epilogue: C/D layout col=lane&15, row=quad*4+reg
    const long long cb = zb * cSB + zh * cSH;
    #pragma unroll
    for (int i = 0; i < MT; i++) {
        #pragma unroll
        for (int j = 0; j < NT; j++) {
            const int col = n0 + wn + j * 16 + l15;
            #pragma unroll
            for (int r = 0; r < 4; r++) {
                const int row = m0 + wm + i * 16 + quad * 4 + r;
                float v = acc[i][j][r] * scale;
                if (BIAS) v += bias[col];
                if (GELU) v = 0.5f * v * (1.0f + erff(v * 0.70710678118654752f));
                if (OUTBF) ((u16t*)Cv)[cb + (long long)row * ldc + col] = f2bf(v);
                else       ((float*)Cv)[cb + (long long)row * ldc + col] = v;
            }
        }
    }
}

// ---------------------------------------------------------------------------
// fp32 W[K][N] (ldw) -> bf16 WT[N][K] (ldt), 32x32 LDS-tiled transpose+convert
// ---------------------------------------------------------------------------
__global__ __launch_bounds__(256) void wconvT(
    const float* __restrict__ W, int ldw, int n_off, long long srcZ,
    u16t* __restrict__ WT, int ldt, long long dstZ)
{
    W  += (long long)blockIdx.z * srcZ;
    WT += (long long)blockIdx.z * dstZ;
    __shared__ float t[32][33];
    const int n0 = blockIdx.x * 32, k0 = blockIdx.y * 32;
    const int c = threadIdx.x & 31, r = threadIdx.x >> 5;
    #pragma unroll
    for (int i = 0; i < 4; i++)
        t[r + i * 8][c] = W[(long long)(k0 + r + i * 8) * ldw + n_off + n0 + c];
    __syncthreads();
    #pragma unroll
    for (int i = 0; i < 4; i++)
        WT[(long long)(n0 + r + i * 8) * ldt + k0 + c] = f2bf(t[c][r + i * 8]);
}

// ---------------------------------------------------------------------------
// Embedding + sinusoidal positional encoding -> fp32 h and bf16 hb
// ---------------------------------------------------------------------------
__global__ __launch_bounds__(256) void embed_pos(
    const int* __restrict__ x, const float* __restrict__ W,
    float* __restrict__ h, u16t* __restrict__ hb)
{
    int idx = blockIdx.x * 256 + threadIdx.x;
    int row = idx >> 9, c = idx & 511;
    int tpos = row & (TSEQ - 1);
    int tok = x[row];
    int i = c >> 1;
    float inv = expf(-9.210340371976184f * ((float)i * (1.0f / 128.0f)));
    float ang = (float)tpos * inv;
    float pe = (c & 1) ? cosf(ang) : sinf(ang);
    float v = W[(long long)tok * KDIM + c] + pe;
    h[idx] = v;
    hb[idx] = f2bf(v);
}

// ---------------------------------------------------------------------------
// LayerNorm over 512, one wave per row; writes fp32 out and bf16 outb.
// NP: number of stacked fp32 partials in A (stride ROWS*KDIM) — split-K
// reduce fused here. GB: add a GEMM bias vector gb[c] (split-K drops the
// GEMM-epilogue bias). RES: add residual R.
// ---------------------------------------------------------------------------
template<int NP, bool GB, bool RES>
__global__ __launch_bounds__(64) void ln512(
    const float* __restrict__ A, const float* __restrict__ R,
    const float* __restrict__ gb,
    const float* __restrict__ w, const float* __restrict__ bias,
    float* __restrict__ out, u16t* __restrict__ outb)
{
    long long row = blockIdx.x;
    int t = threadIdx.x;
    const float* a = A + row * KDIM;
    float4 u0 = *(const float4*)&a[t * 4];
    float4 u1 = *(const float4*)&a[256 + t * 4];
    if (NP == 2) {
        const float* a2 = A + (long long)ROWS * KDIM + row * KDIM;
        float4 p0 = *(const float4*)&a2[t * 4];
        float4 p1 = *(const float4*)&a2[256 + t * 4];
        u0.x += p0.x; u0.y += p0.y; u0.z += p0.z; u0.w += p0.w;
        u1.x += p1.x; u1.y += p1.y; u1.z += p1.z; u1.w += p1.w;
    }
    if (GB) {
        float4 g0 = *(const float4*)&gb[t * 4];
        float4 g1 = *(const float4*)&gb[256 + t * 4];
        u0.x += g0.x; u0.y += g0.y; u0.z += g0.z; u0.w += g0.w;
        u1.x += g1.x; u1.y += g1.y; u1.z += g1.z; u1.w += g1.w;
    }
    if (RES) {
        const float* rr = R + row * KDIM;
        float4 r0 = *(const float4*)&rr[t * 4];
        float4 r1 = *(const float4*)&rr[256 + t * 4];
        u0.x += r0.x; u0.y += r0.y; u0.z += r0.z; u0.w += r0.w;
        u1.x += r1.x; u1.y += r1.y; u1.z += r1.z; u1.w += r1.w;
    }
    float xv[8] = {u0.x, u0.y, u0.z, u0.w, u1.x, u1.y, u1.z, u1.w};
    float s = 0.f;
    #pragma unroll
    for (int e = 0; e < 8; e++) s += xv[e];
    #pragma unroll
    for (int off = 32; off; off >>= 1) s += __shfl_xor(s, off);
    float mean = s * (1.0f / 512.0f);
    float vs = 0.f;
    #pragma unroll
    for (int e = 0; e < 8; e++) { float d = xv[e] - mean; vs += d * d; }
    #pragma unroll
    for (int off = 32; off; off >>= 1) vs += __shfl_xor(vs, off);
    float rstd = rsqrtf(vs * (1.0f / 512.0f) + 1e-5f);

    int c0 = t * 4, c1 = 256 + t * 4;
    #pragma unroll
    for (int e = 0; e < 8; e++) {
        int c = (e < 4) ? (c0 + e) : (c1 + e - 4);
        float o = (xv[e] - mean) * rstd * w[c] + bias[c];
        out[row * KDIM + c] = o;
        outb[row * KDIM + c] = f2bf(o);
    }
}

// ---------------------------------------------------------------------------
// Row softmax over 512 (fp32 in -> bf16 out), one wave per row.
// Applies the causal mask itself (c > r -> -1e30) so the scores GEMM never
// has to write masked tiles; never-written regions (arbitrary garbage,
// possibly NaN) are clobbered before any use.
// ---------------------------------------------------------------------------
__global__ __launch_bounds__(64) void softmax512b(
    const float* __restrict__ S, u16t* __restrict__ P)
{
    long long base = (long long)blockIdx.x * 512;
    const int r = blockIdx.x & (TSEQ - 1);
    int t = threadIdx.x;
    float4 u0 = *(const float4*)&S[base + t * 4];
    float4 u1 = *(const float4*)&S[base + 256 + t * 4];
    float xv[8] = {u0.x, u0.y, u0.z, u0.w, u1.x, u1.y, u1.z, u1.w};
    #pragma unroll
    for (int e = 0; e < 8; e++) {
        int c = (e < 4) ? (t * 4 + e) : (256 + t * 4 + e - 4);
        if (c > r) xv[e] = -1e30f;     // causal mask (also kills garbage/NaN)
    }
    float m = xv[0];
    #pragma unroll
    for (int e = 1; e < 8; e++) m = fmaxf(m, xv[e]);
    #pragma unroll
    for (int off = 32; off; off >>= 1) m = fmaxf(m, __shfl_xor(m, off));
    float s = 0.f;
    #pragma unroll
    for (int e = 0; e < 8; e++) { xv[e] = expf(xv[e] - m); s += xv[e]; }
    #pragma unroll
    for (int off = 32; off; off >>= 1) s += __shfl_xor(s, off);
    float inv = 1.0f / s;
    #pragma unroll
    for (int e = 0; e < 8; e++) {
        int c = (e < 4) ? (t * 4 + e) : (256 + t * 4 + e - 4);
        P[base + c] = f2bf(xv[e] * inv);
    }
}

// ---------------------------------------------------------------------------
extern "C" void kernel_launch(void* const* d_in, const int* in_sizes, int n_in,
                              void* d_out, int out_size, void* d_ws, size_t ws_size,
                              hipStream_t stream)
{
    const int*   x      = (const int*)  d_in[0];
    const float* embedW = (const float*)d_in[1];
    const float* Wq     = (const float*)d_in[2];
    const float* Wk     = (const float*)d_in[3];
    const float* Wv     = (const float*)d_in[4];
    const float* Wu     = (const float*)d_in[5];
    const float* bu     = (const float*)d_in[6];
    const float* W1     = (const float*)d_in[7];
    const float* b1     = (const float*)d_in[8];
    const float* W2     = (const float*)d_in[9];
    const float* b2     = (const float*)d_in[10];
    const float* ln1w   = (const float*)d_in[11];
    const float* ln1b   = (const float*)d_in[12];
    const float* ln2w   = (const float*)d_in[13];
    const float* ln2b   = (const float*)d_in[14];
    const float* lnfw   = (const float*)d_in[15];
    const float* lnfb   = (const float*)d_in[16];
    const float* unembW = (const float*)d_in[17];
    const float* unembB = (const float*)d_in[18];

    char* ob = (char*)d_out;
    float* outF = (float*)d_out;

    // ---- d_out scratch layout (bytes). All dead before the final 5 unembed
    // GEMMs overwrite d_out column-chunk by column-chunk.
    u16t*  wb  = (u16t*)(ob);                  // bf16^T weights, 4 x 10,485,760 u16
    u16t*  qk  = (u16t*)(ob + 83886080);       // [2048 x 8192] bf16 (Q|K fused)
    u16t*  vt  = (u16t*)(ob + 117440512);      // [4096 x 2048] bf16 (V^T)
    float* sc  = (float*)(ob + 134217728);     // [32 x 512 x 512] fp32 scores
    u16t*  Pb  = (u16t*) (ob + 167772160);     // [32 x 512 x 512] bf16 probs
    u16t*  y   = (u16t*) (ob + 184549376);     // [2048 x 4096] bf16
    u16t*  f1  = (u16t*) (ob + 201326592);     // [2048 x 2048] bf16
    float* tmp = (float*)(ob + 209715200);     // 2 x [2048 x 512] fp32 split-K partials
    float* ff2 = (float*)(ob + 218103808);     // 2 x [2048 x 512] fp32 split-K partials
    float* h   = (float*)(ob + 226492416);     // [2048 x 512] fp32 residual
    float* h2  = (float*)(ob + 230686720);     // [2048 x 512] fp32
    u16t*  hb  = (u16t*) (ob + 234881024);     // bf16 of h
    u16t*  h2b = (u16t*) (ob + 236978176);     // bf16 of h2   (end 239,075,328)

    // ---- d_ws: only what must survive the final GEMMs (8.65 MB)
    char* wsb = (char*)d_ws;
    u16t* hf  = (u16t*)(wsb);                  // [2048 x 512] bf16 final-LN
    u16t* wun = (u16t*)(wsb + 2097152);        // [6400 x 512] bf16 unembed chunk

    // per-block bf16^T weight offsets (u16 elements)
    const long long WBLK = 10485760;
    const long long OQ = 0, OK_ = 2097152, OV = 4194304, OU = 6291456,
                    O1 = 8388608, O2 = 9437184;

    const float inv_sqrt_k = 0.04419417382415922f;
    const long long z0 = 0;

    // ---- weight convert+transpose (all blocks batched via grid.z) ----
    wconvT<<<dim3(DMODEL/32, KDIM/32, NBLK), 256, 0, stream>>>(
        Wq, DMODEL, 0, (long long)KDIM*DMODEL, wb + OQ, KDIM, WBLK);
    wconvT<<<dim3(DMODEL/32, KDIM/32, NBLK), 256, 0, stream>>>(
        Wk, DMODEL, 0, (long long)KDIM*DMODEL, wb + OK_, KDIM, WBLK);
    wconvT<<<dim3(DMODEL/32, KDIM/32, NBLK), 256, 0, stream>>>(
        Wv, DMODEL, 0, (long long)KDIM*DMODEL, wb + OV, KDIM, WBLK);
    wconvT<<<dim3(KDIM/32, DMODEL/32, NBLK), 256, 0, stream>>>(
        Wu, KDIM, 0, (long long)DMODEL*KDIM, wb + OU, DMODEL, WBLK);
    wconvT<<<dim3(FFDIM/32, KDIM/32, NBLK), 256, 0, stream>>>(
        W1, FFDIM, 0, (long long)KDIM*FFDIM, wb + O1, KDIM, WBLK);
    wconvT<<<dim3(KDIM/32, FFDIM/32, NBLK), 256, 0, stream>>>(
        W2, KDIM, 0, (long long)FFDIM*KDIM, wb + O2, FFDIM, WBLK);

    embed_pos<<<ROWS * KDIM / 256, 256, 0, stream>>>(x, embedW, h, hb);

    for (int i = 0; i < NBLK; i++) {
        u16t* wbi = wb + (long long)i * WBLK;

        // QK fused: [2048x512] @ [512x8192] -> qk bf16
        gemm_bf16<128,128,true,false,false,false,false>
            <<<dim3(64, 16, 1), 256, 0, stream>>>(
            hb, wbi + OQ, nullptr, qk, KDIM, KDIM, KDIM, 2*DMODEL,
            z0,z0,z0,z0,z0,z0, 1, 1.0f);

        // V^T = WvT @ h^T: [4096x512] x [2048x512]^T -> vt bf16 [4096x2048]
        gemm_bf16<128,128,true,false,false,false,false>
            <<<dim3(16, 32, 1), 256, 0, stream>>>(
            wbi + OV, hb, nullptr, vt, KDIM, KDIM, KDIM, ROWS,
            z0,z0,z0,z0,z0,z0, 1, 1.0f);

        // scores = Q K^T / sqrt(512), lower-triangle tiles only -> sc fp32
        gemm_bf16<128,128,false,false,false,true,false>
            <<<dim3(4, 4, BATCH_*HEADS), 256, 0, stream>>>(
            qk, qk + DMODEL, nullptr, sc, KDIM, 2*DMODEL, 2*DMODEL, TSEQ,
            (long long)TSEQ*2*DMODEL, (long long)KDIM,
            (long long)TSEQ*2*DMODEL, (long long)KDIM,
            (long long)HEADS*TSEQ*TSEQ, (long long)TSEQ*TSEQ, HEADS, inv_sqrt_k);

        softmax512b<<<BATCH_*HEADS*TSEQ, 64, 0, stream>>>(sc, Pb);

        // y = P @ V  (per b,h), triangular K-limit -> y bf16 [2048x4096]
        gemm_bf16<128,128,true,false,false,false,true>
            <<<dim3(4, 4, BATCH_*HEADS), 256, 0, stream>>>(
            Pb, vt, nullptr, y, TSEQ, TSEQ, ROWS, DMODEL,
            (long long)HEADS*TSEQ*TSEQ, (long long)TSEQ*TSEQ,
            (long long)TSEQ, (long long)TSEQ*ROWS,
            (long long)TSEQ*DMODEL, (long long)KDIM, HEADS, 1.0f);

        // out-proj: [2048x4096] @ [4096x512], split-K2 -> tmp partials (512 blocks)
        gemm_bf16<64,64,false,false,false,false,false>
            <<<dim3(8, 32, 2), 256, 0, stream>>>(
            y, wbi + OU, nullptr, tmp, DMODEL/2, DMODEL, DMODEL, KDIM,
            (long long)(DMODEL/2), z0, (long long)(DMODEL/2), z0,
            (long long)ROWS*KDIM, z0, 1, 1.0f);

        // ln1 reduces split-K partials + bu + residual h
        ln512<2,true,true><<<ROWS, 64, 0, stream>>>(
            tmp, h, bu + i*KDIM, ln1w + i*KDIM, ln1b + i*KDIM, h2, h2b);

        // ffn1 = gelu(h2 @ W1 + b1) -> f1 bf16 [2048x2048]  (64x128: 512 blocks)
        gemm_bf16<64,128,true,true,true,false,false>
            <<<dim3(16, 32, 1), 256, 0, stream>>>(
            h2b, wbi + O1, b1 + i*FFDIM, f1, KDIM, KDIM, KDIM, FFDIM,
            z0,z0,z0,z0,z0,z0, 1, 1.0f);

        // ffn2 = f1 @ W2, split-K2 -> ff2 partials (512 blocks)
        gemm_bf16<64,64,false,false,false,false,false>
            <<<dim3(8, 32, 2), 256, 0, stream>>>(
            f1, wbi + O2, nullptr, ff2, FFDIM/2, FFDIM, FFDIM, KDIM,
            (long long)(FFDIM/2), z0, (long long)(FFDIM/2), z0,
            (long long)ROWS*KDIM, z0, 1, 1.0f);

        // ln2 reduces split-K partials + b2 + residual h2
        ln512<2,true,true><<<ROWS, 64, 0, stream>>>(
            ff2, h2, b2 + i*KDIM, ln2w + i*KDIM, ln2b + i*KDIM, h, hb);
    }

    // final LN (fp32 out goes to dead tmp; hf bf16 is what we need)
    ln512<1,false,false><<<ROWS, 64, 0, stream>>>(
        h, nullptr, nullptr, lnfw, lnfb, tmp, hf);

    // unembed in 5 column chunks of 6400 (weight chunk converted into ws)
    const int CH = 6400;
    for (int c = 0; c < 5; c++) {
        wconvT<<<dim3(CH/32, KDIM/32, 1), 256, 0, stream>>>(
            unembW, VOCAB_, c*CH, z0, wun, KDIM, z0);
        gemm_bf16<128,128,false,true,false,false,false>
            <<<dim3(CH/128, 16, 1), 256, 0, stream>>>(
            hf, wun, unembB + c*CH, outF + c*CH, KDIM, KDIM, KDIM, VOCAB_,
            z0,z0,z0,z0,z0,z0, 1, 1.0f);
    }
}

// Round 3
// 1118.733 us; speedup vs baseline: 1.2615x; 1.0569x over previous
//
#include <hip/hip_runtime.h>
#include <math.h>
#include <stdint.h>

#define KDIM 512
#define HEADS 8
#define NBLK 4
#define TSEQ 512
#define BATCH_ 4
#define ROWS 2048
#define DMODEL 4096
#define VOCAB_ 32000
#define FFDIM 2048

typedef __attribute__((ext_vector_type(4))) float f32x4;
typedef __attribute__((ext_vector_type(8))) short s16x8;
typedef unsigned short u16t;

// fp32 -> bf16 round-to-nearest-even
__device__ __forceinline__ u16t f2bf(float f) {
    union { float f; unsigned u; } cv; cv.f = f;
    return (u16t)((cv.u + 0x7FFFu + ((cv.u >> 16) & 1u)) >> 16);
}

// async 16B global -> LDS (wave-uniform LDS base + lane*16). CK-style casts.
__device__ __forceinline__ void gload_lds16(const void* g, void* lds) {
    __builtin_amdgcn_global_load_lds(
        (const __attribute__((address_space(1))) unsigned int*)(uintptr_t)g,
        (__attribute__((address_space(3))) unsigned int*)(unsigned int)(uintptr_t)lds,
        16, 0, 0);
}

// ---------------------------------------------------------------------------
// Shared GEMM body, TRANSB form: C[m][n] = scale * sum_k A[m][k] * Bt[n][k]
// A: [M x K] bf16 row-major (lda), Bt: [N x K] bf16 row-major (ldb).
// BM x BN tile, 256 threads = 4 waves (2x2), each wave BM/2 x BN/2 via
// 16x16x32 MFMAs. BK=64: one barrier-pair covers two 32-k MFMA groups.
// LDS staged via global_load_lds(16B) with a full 3-bit XOR swizzle on the
// 16B k-chunk: phys = kc ^ (row & 7) -> fragment ds_read_b128 is 2-way
// bank-aliased (free on CDNA4, m136).
// ---------------------------------------------------------------------------
template<int BM, int BN, bool OUTBF, bool BIAS, bool GELU, bool KTRI>
__device__ __forceinline__ void gemm_body(
    const u16t* __restrict__ A, const u16t* __restrict__ Bt,
    const float* __restrict__ bias, void* __restrict__ Cv,
    int Kd, int lda, int ldb, int ldc, long long cb,
    int m0, int n0, float scale)
{
    const int tid = threadIdx.x;
    const int wave = tid >> 6, lane = tid & 63;
    const int quad = lane >> 4, l15 = lane & 15;
    const int wm = (wave >> 1) * (BM / 2), wn = (wave & 1) * (BN / 2);
    constexpr int MT = BM / 32, NT = BN / 32;

    __shared__ __align__(16) u16t As[BM * 64];
    __shared__ __align__(16) u16t Bs[BN * 64];

    f32x4 acc[MT][NT];
    #pragma unroll
    for (int i = 0; i < MT; i++)
        #pragma unroll
        for (int j = 0; j < NT; j++)
            acc[i][j] = (f32x4){0.f, 0.f, 0.f, 0.f};

    const int kend = KTRI ? (Kd < m0 + BM ? Kd : m0 + BM) : Kd;

    for (int k0 = 0; k0 < kend; k0 += 64) {
        #pragma unroll
        for (int r = 0; r < BM / 32; ++r) {
            int cc = r * 256 + tid;
            int row = cc >> 3, pc = cc & 7;          // 8 x 16B chunks per row
            int kc = pc ^ (row & 7);                 // involution swizzle
            gload_lds16(A + (long long)(m0 + row) * lda + k0 + kc * 8, &As[cc * 8]);
        }
        #pragma unroll
        for (int r = 0; r < BN / 32; ++r) {
            int cc = r * 256 + tid;
            int row = cc >> 3, pc = cc & 7;
            int kc = pc ^ (row & 7);
            gload_lds16(Bt + (long long)(n0 + row) * ldb + k0 + kc * 8, &Bs[cc * 8]);
        }
        __syncthreads();   // drains vmcnt for the LDS DMA

        #pragma unroll
        for (int g = 0; g < 2; ++g) {                // two 32-k MFMA groups
            s16x8 af[MT], bfr[NT];
            #pragma unroll
            for (int i = 0; i < MT; i++) {
                int row = wm + i * 16 + l15;
                int pc = (g * 4 + quad) ^ (row & 7);
                af[i] = *(const s16x8*)&As[row * 64 + pc * 8];
            }
            #pragma unroll
            for (int j = 0; j < NT; j++) {
                int row = wn + j * 16 + l15;
                int pc = (g * 4 + quad) ^ (row & 7);
                bfr[j] = *(const s16x8*)&Bs[row * 64 + pc * 8];
            }
            #pragma unroll
            for (int i = 0; i < MT; i++)
                #pragma unroll
                for (int j = 0; j < NT; j++)
                    acc[i][j] = __builtin_amdgcn_mfma_f32_16x16x32_bf16(
                        af[i], bfr[j], acc[i][j], 0, 0, 0);
        }
        __syncthreads();
    }

    // epilogue: C/D layout col=lane&15, row=quad*4+reg
    #pragma unroll
    for (int i = 0; i < MT; i++) {
        #pragma unroll
        for (int j = 0; j < NT; j++) {
            const int col = n0 + wn + j * 16 + l15;
            #pragma unroll
            for (int r = 0; r < 4; r++) {
                const int row = m0 + wm + i * 16 + quad * 4 + r;
                float v = acc[i][j][r] * scale;
                if (BIAS) v += bias[col];
                if (GELU) v = 0.5f * v * (1.0f + erff(v * 0.70710678118654752f));
                if (OUTBF) ((u16t*)Cv)[cb + (long long)row * ldc + col] = f2bf(v);
                else       ((float*)Cv)[cb + (long long)row * ldc + col] = v;
            }
        }
    }
}

// General wrapper. Batched over blockIdx.z with (zb, zh) two-level strides;
// split-K via the same strides (aSB/bSB = k offset, cSB = partial offset,
// Hn=1). MASK: tiles above the diagonal return (softmax masks in-tile).
// KTRI: triangular K-limit + descending-m launch order (long blocks first).
template<int BM, int BN, bool OUTBF, bool BIAS, bool GELU, bool MASK, bool KTRI>
__global__ __launch_bounds__(256, 2) void gemm_bf16(
    const u16t* __restrict__ A, const u16t* __restrict__ Bt,
    const float* __restrict__ bias, void* __restrict__ Cv,
    int Kd, int lda, int ldb, int ldc,
    long long aSB, long long aSH, long long bSB, long long bSH,
    long long cSB, long long cSH, int Hn, float scale)
{
    const int by = KTRI ? (gridDim.y - 1 - blockIdx.y) : blockIdx.y;
    const int m0 = by * BM, n0 = blockIdx.x * BN;
    if (MASK && n0 > m0) return;      // fully-masked tile: softmax handles it
    const int zb = blockIdx.z / Hn, zh = blockIdx.z % Hn;
    gemm_body<BM, BN, OUTBF, BIAS, GELU, KTRI>(
        A + zb * aSB + zh * aSH, Bt + zb * bSB + zh * bSH, bias, Cv,
        Kd, lda, ldb, ldc, zb * cSB + zh * cSH, m0, n0, scale);
}

// Fused QK + V^T dispatch: both depend only on hb; one grid of 1536 blocks
// (1024 QK tiles then 512 V^T tiles) so V^T backfills QK's scheduling tail.
__global__ __launch_bounds__(256, 2) void gemm_qkvt(
    const u16t* __restrict__ hb, const u16t* __restrict__ wq,
    u16t* __restrict__ qk, const u16t* __restrict__ wv,
    u16t* __restrict__ vt)
{
    const int bx = blockIdx.x;
    const u16t* A; const u16t* Bt; u16t* C; int ldc, m0, n0;
    if (bx < 1024) {       // QK: [2048x512] @ [512x8192]^T-form -> qk
        A = hb; Bt = wq; C = qk; ldc = 2 * DMODEL;
        n0 = (bx & 63) * 128; m0 = (bx >> 6) * 128;
    } else {               // V^T: [4096x512] @ [2048x512]^T-form -> vt
        int i = bx - 1024;
        A = wv; Bt = hb; C = vt; ldc = ROWS;
        n0 = (i & 15) * 128; m0 = (i >> 4) * 128;
    }
    gemm_body<128, 128, true, false, false, false>(
        A, Bt, nullptr, C, KDIM, KDIM, KDIM, ldc, 0, m0, n0, 1.0f);
}

// ---------------------------------------------------------------------------
// fp32 W[K][N] (ldw) -> bf16 WT[N][K] (ldt), 32x32 LDS-tiled transpose+convert
// ---------------------------------------------------------------------------
__global__ __launch_bounds__(256) void wconvT(
    const float* __restrict__ W, int ldw, int n_off, long long srcZ,
    u16t* __restrict__ WT, int ldt, long long dstZ)
{
    W  += (long long)blockIdx.z * srcZ;
    WT += (long long)blockIdx.z * dstZ;
    __shared__ float t[32][33];
    const int n0 = blockIdx.x * 32, k0 = blockIdx.y * 32;
    const int c = threadIdx.x & 31, r = threadIdx.x >> 5;
    #pragma unroll
    for (int i = 0; i < 4; i++)
        t[r + i * 8][c] = W[(long long)(k0 + r + i * 8) * ldw + n0 + c + n_off];
    __syncthreads();
    #pragma unroll
    for (int i = 0; i < 4; i++)
        WT[(long long)(n0 + r + i * 8) * ldt + k0 + c] = f2bf(t[c][r + i * 8]);
}

// Batched 3-tensor variant for Wq/Wk/Wv (identical [512 x 4096] shape x NBLK).
__global__ __launch_bounds__(256) void wconvT3(
    const float* __restrict__ W0, const float* __restrict__ W1,
    const float* __restrict__ W2, long long srcZ,
    u16t* __restrict__ WT, long long dstZ, long long dstG)
{
    const int zi = blockIdx.z >> 2, zb = blockIdx.z & 3;   // NBLK = 4
    const float* W = (zi == 0 ? W0 : zi == 1 ? W1 : W2) + zb * srcZ;
    u16t* D = WT + zi * dstG + zb * dstZ;
    __shared__ float t[32][33];
    const int n0 = blockIdx.x * 32, k0 = blockIdx.y * 32;
    const int c = threadIdx.x & 31, r = threadIdx.x >> 5;
    #pragma unroll
    for (int i = 0; i < 4; i++)
        t[r + i * 8][c] = W[(long long)(k0 + r + i * 8) * DMODEL + n0 + c];
    __syncthreads();
    #pragma unroll
    for (int i = 0; i < 4; i++)
        D[(long long)(n0 + r + i * 8) * KDIM + k0 + c] = f2bf(t[c][r + i * 8]);
}

// ---------------------------------------------------------------------------
// Embedding + sinusoidal positional encoding -> fp32 h and bf16 hb
// ---------------------------------------------------------------------------
__global__ __launch_bounds__(256) void embed_pos(
    const int* __restrict__ x, const float* __restrict__ W,
    float* __restrict__ h, u16t* __restrict__ hb)
{
    int idx = blockIdx.x * 256 + threadIdx.x;
    int row = idx >> 9, c = idx & 511;
    int tpos = row & (TSEQ - 1);
    int tok = x[row];
    int i = c >> 1;
    float inv = expf(-9.210340371976184f * ((float)i * (1.0f / 128.0f)));
    float ang = (float)tpos * inv;
    float pe = (c & 1) ? cosf(ang) : sinf(ang);
    float v = W[(long long)tok * KDIM + c] + pe;
    h[idx] = v;
    hb[idx] = f2bf(v);
}

// ---------------------------------------------------------------------------
// LayerNorm over 512; 256 threads = 4 waves, one row per wave (grid = rows/4).
// NP: stacked fp32 split-K partials in A (stride ROWS*KDIM), reduced here.
// GB: add GEMM bias vector gb[c]. RES: add residual R.
// ---------------------------------------------------------------------------
template<int NP, bool GB, bool RES>
__global__ __launch_bounds__(256) void ln512(
    const float* __restrict__ A, const float* __restrict__ R,
    const float* __restrict__ gb,
    const float* __restrict__ w, const float* __restrict__ bias,
    float* __restrict__ out, u16t* __restrict__ outb)
{
    const int wv = threadIdx.x >> 6, t = threadIdx.x & 63;
    long long row = (long long)blockIdx.x * 4 + wv;
    const float* a = A + row * KDIM;
    float4 u0 = *(const float4*)&a[t * 4];
    float4 u1 = *(const float4*)&a[256 + t * 4];
    #pragma unroll
    for (int p = 1; p < NP; ++p) {
        const float* ap = a + (long long)p * ROWS * KDIM;
        float4 p0 = *(const float4*)&ap[t * 4];
        float4 p1 = *(const float4*)&ap[256 + t * 4];
        u0.x += p0.x; u0.y += p0.y; u0.z += p0.z; u0.w += p0.w;
        u1.x += p1.x; u1.y += p1.y; u1.z += p1.z; u1.w += p1.w;
    }
    if (GB) {
        float4 g0 = *(const float4*)&gb[t * 4];
        float4 g1 = *(const float4*)&gb[256 + t * 4];
        u0.x += g0.x; u0.y += g0.y; u0.z += g0.z; u0.w += g0.w;
        u1.x += g1.x; u1.y += g1.y; u1.z += g1.z; u1.w += g1.w;
    }
    if (RES) {
        const float* rr = R + row * KDIM;
        float4 r0 = *(const float4*)&rr[t * 4];
        float4 r1 = *(const float4*)&rr[256 + t * 4];
        u0.x += r0.x; u0.y += r0.y; u0.z += r0.z; u0.w += r0.w;
        u1.x += r1.x; u1.y += r1.y; u1.z += r1.z; u1.w += r1.w;
    }
    float xv[8] = {u0.x, u0.y, u0.z, u0.w, u1.x, u1.y, u1.z, u1.w};
    float s = 0.f;
    #pragma unroll
    for (int e = 0; e < 8; e++) s += xv[e];
    #pragma unroll
    for (int off = 32; off; off >>= 1) s += __shfl_xor(s, off);
    float mean = s * (1.0f / 512.0f);
    float vs = 0.f;
    #pragma unroll
    for (int e = 0; e < 8; e++) { float d = xv[e] - mean; vs += d * d; }
    #pragma unroll
    for (int off = 32; off; off >>= 1) vs += __shfl_xor(vs, off);
    float rstd = rsqrtf(vs * (1.0f / 512.0f) + 1e-5f);

    int c0 = t * 4, c1 = 256 + t * 4;
    #pragma unroll
    for (int e = 0; e < 8; e++) {
        int c = (e < 4) ? (c0 + e) : (c1 + e - 4);
        float o = (xv[e] - mean) * rstd * w[c] + bias[c];
        out[row * KDIM + c] = o;
        outb[row * KDIM + c] = f2bf(o);
    }
}

// ---------------------------------------------------------------------------
// Row softmax over 512 (fp32 in -> bf16 out); 4 waves/block, one row per wave.
// Applies the causal mask itself (c > r -> -1e30) so the scores GEMM never
// writes masked tiles; never-written garbage is clobbered before any use.
// ---------------------------------------------------------------------------
__global__ __launch_bounds__(256) void softmax512b(
    const float* __restrict__ S, u16t* __restrict__ P)
{
    const int wv = threadIdx.x >> 6, t = threadIdx.x & 63;
    long long row = (long long)blockIdx.x * 4 + wv;
    long long base = row * 512;
    const int r = (int)(row & (TSEQ - 1));
    float4 u0 = *(const float4*)&S[base + t * 4];
    float4 u1 = *(const float4*)&S[base + 256 + t * 4];
    float xv[8] = {u0.x, u0.y, u0.z, u0.w, u1.x, u1.y, u1.z, u1.w};
    #pragma unroll
    for (int e = 0; e < 8; e++) {
        int c = (e < 4) ? (t * 4 + e) : (256 + t * 4 + e - 4);
        if (c > r) xv[e] = -1e30f;     // causal mask (also kills garbage/NaN)
    }
    float m = xv[0];
    #pragma unroll
    for (int e = 1; e < 8; e++) m = fmaxf(m, xv[e]);
    #pragma unroll
    for (int off = 32; off; off >>= 1) m = fmaxf(m, __shfl_xor(m, off));
    float s = 0.f;
    #pragma unroll
    for (int e = 0; e < 8; e++) { xv[e] = expf(xv[e] - m); s += xv[e]; }
    #pragma unroll
    for (int off = 32; off; off >>= 1) s += __shfl_xor(s, off);
    float inv = 1.0f / s;
    #pragma unroll
    for (int e = 0; e < 8; e++) {
        int c = (e < 4) ? (t * 4 + e) : (256 + t * 4 + e - 4);
        P[base + c] = f2bf(xv[e] * inv);
    }
}

// ---------------------------------------------------------------------------
extern "C" void kernel_launch(void* const* d_in, const int* in_sizes, int n_in,
                              void* d_out, int out_size, void* d_ws, size_t ws_size,
                              hipStream_t stream)
{
    const int*   x      = (const int*)  d_in[0];
    const float* embedW = (const float*)d_in[1];
    const float* Wq     = (const float*)d_in[2];
    const float* Wk     = (const float*)d_in[3];
    const float* Wv     = (const float*)d_in[4];
    const float* Wu     = (const float*)d_in[5];
    const float* bu     = (const float*)d_in[6];
    const float* W1     = (const float*)d_in[7];
    const float* b1     = (const float*)d_in[8];
    const float* W2     = (const float*)d_in[9];
    const float* b2     = (const float*)d_in[10];
    const float* ln1w   = (const float*)d_in[11];
    const float* ln1b   = (const float*)d_in[12];
    const float* ln2w   = (const float*)d_in[13];
    const float* ln2b   = (const float*)d_in[14];
    const float* lnfw   = (const float*)d_in[15];
    const float* lnfb   = (const float*)d_in[16];
    const float* unembW = (const float*)d_in[17];
    const float* unembB = (const float*)d_in[18];

    char* ob = (char*)d_out;
    float* outF = (float*)d_out;

    // ---- d_out scratch layout (bytes). All dead before the final unembed
    // GEMM(s) overwrite d_out.
    u16t*  wb  = (u16t*)(ob);                  // bf16^T weights, 4 x 10,485,760 u16
    u16t*  qk  = (u16t*)(ob + 83886080);       // [2048 x 8192] bf16 (Q|K fused)
    u16t*  vt  = (u16t*)(ob + 117440512);      // [4096 x 2048] bf16 (V^T)
    float* sc  = (float*)(ob + 134217728);     // [32 x 512 x 512] fp32 scores
                                               //  (doubles as 8 x [2048x512] fp32
                                               //   out-proj split-K partials: 33.55 MB)
    u16t*  Pb  = (u16t*) (ob + 167772160);     // [32 x 512 x 512] bf16 probs
    u16t*  y   = (u16t*) (ob + 184549376);     // [2048 x 4096] bf16
    u16t*  f1  = (u16t*) (ob + 201326592);     // [2048 x 2048] bf16
    float* ff2 = (float*)(ob + 218103808);     // 2 x [2048 x 512] fp32 split-K partials
    float* h   = (float*)(ob + 226492416);     // [2048 x 512] fp32 residual
    float* h2  = (float*)(ob + 230686720);     // [2048 x 512] fp32
    u16t*  hb  = (u16t*) (ob + 234881024);     // bf16 of h
    u16t*  h2b = (u16t*) (ob + 236978176);     // bf16 of h2   (end 239,075,328)
    float* tmp = sc;                           // out-proj partials alias (sc dead then)

    // ---- d_ws: only what must survive the final GEMMs
    char* wsb = (char*)d_ws;
    u16t* hf  = (u16t*)(wsb);                  // [2048 x 512] bf16 final-LN
    u16t* wun = (u16t*)(wsb + 2097152);        // bf16 unembed weight (chunk or full)

    // per-block bf16^T weight offsets (u16 elements)
    const long long WBLK = 10485760;
    const long long OQ = 0, OV = 4194304, OU = 6291456,
                    O1 = 8388608, O2 = 9437184;

    const float inv_sqrt_k = 0.04419417382415922f;
    const long long z0 = 0;

    // ---- weight convert+transpose ----
    wconvT3<<<dim3(DMODEL/32, KDIM/32, 3*NBLK), 256, 0, stream>>>(
        Wq, Wk, Wv, (long long)KDIM*DMODEL, wb, WBLK, 2097152);
    wconvT<<<dim3(KDIM/32, DMODEL/32, NBLK), 256, 0, stream>>>(
        Wu, KDIM, 0, (long long)DMODEL*KDIM, wb + OU, DMODEL, WBLK);
    wconvT<<<dim3(FFDIM/32, KDIM/32, NBLK), 256, 0, stream>>>(
        W1, FFDIM, 0, (long long)KDIM*FFDIM, wb + O1, KDIM, WBLK);
    wconvT<<<dim3(KDIM/32, FFDIM/32, NBLK), 256, 0, stream>>>(
        W2, KDIM, 0, (long long)FFDIM*KDIM, wb + O2, FFDIM, WBLK);

    embed_pos<<<ROWS * KDIM / 256, 256, 0, stream>>>(x, embedW, h, hb);

    for (int i = 0; i < NBLK; i++) {
        u16t* wbi = wb + (long long)i * WBLK;

        // QK fused + V^T in ONE dispatch (both read only hb)
        gemm_qkvt<<<dim3(1536, 1, 1), 256, 0, stream>>>(
            hb, wbi + OQ, qk, wbi + OV, vt);

        // scores = Q K^T / sqrt(512), lower-triangle tiles only -> sc fp32
        gemm_bf16<128,128,false,false,false,true,false>
            <<<dim3(4, 4, BATCH_*HEADS), 256, 0, stream>>>(
            qk, qk + DMODEL, nullptr, sc, KDIM, 2*DMODEL, 2*DMODEL, TSEQ,
            (long long)TSEQ*2*DMODEL, (long long)KDIM,
            (long long)TSEQ*2*DMODEL, (long long)KDIM,
            (long long)HEADS*TSEQ*TSEQ, (long long)TSEQ*TSEQ, HEADS, inv_sqrt_k);

        softmax512b<<<BATCH_*HEADS*TSEQ/4, 256, 0, stream>>>(sc, Pb);

        // y = P @ V  (per b,h), triangular K-limit, long tiles first -> y bf16
        gemm_bf16<128,128,true,false,false,false,true>
            <<<dim3(4, 4, BATCH_*HEADS), 256, 0, stream>>>(
            Pb, vt, nullptr, y, TSEQ, TSEQ, ROWS, DMODEL,
            (long long)HEADS*TSEQ*TSEQ, (long long)TSEQ*TSEQ,
            (long long)TSEQ, (long long)TSEQ*ROWS,
            (long long)TSEQ*DMODEL, (long long)KDIM, HEADS, 1.0f);

        // out-proj: [2048x4096] @ [4096x512], 128^2 tile split-K8 -> tmp (512 blocks)
        gemm_bf16<128,128,false,false,false,false,false>
            <<<dim3(4, 16, 8), 256, 0, stream>>>(
            y, wbi + OU, nullptr, tmp, DMODEL/8, DMODEL, DMODEL, KDIM,
            (long long)(DMODEL/8), z0, (long long)(DMODEL/8), z0,
            (long long)ROWS*KDIM, z0, 1, 1.0f);

        // ln1 reduces 8 split-K partials + bu + residual h
        ln512<8,true,true><<<ROWS/4, 256, 0, stream>>>(
            tmp, h, bu + i*KDIM, ln1w + i*KDIM, ln1b + i*KDIM, h2, h2b);

        // ffn1 = gelu(h2 @ W1 + b1) -> f1 bf16 [2048x2048]  (64x128: 512 blocks)
        gemm_bf16<64,128,true,true,true,false,false>
            <<<dim3(16, 32, 1), 256, 0, stream>>>(
            h2b, wbi + O1, b1 + i*FFDIM, f1, KDIM, KDIM, KDIM, FFDIM,
            z0,z0,z0,z0,z0,z0, 1, 1.0f);

        // ffn2 = f1 @ W2, split-K2 -> ff2 partials (512 blocks)
        gemm_bf16<64,64,false,false,false,false,false>
            <<<dim3(8, 32, 2), 256, 0, stream>>>(
            f1, wbi + O2, nullptr, ff2, FFDIM/2, FFDIM, FFDIM, KDIM,
            (long long)(FFDIM/2), z0, (long long)(FFDIM/2), z0,
            (long long)ROWS*KDIM, z0, 1, 1.0f);

        // ln2 reduces split-K partials + b2 + residual h2
        ln512<2,true,true><<<ROWS/4, 256, 0, stream>>>(
            ff2, h2, b2 + i*KDIM, ln2w + i*KDIM, ln2b + i*KDIM, h, hb);
    }

    // final LN (fp32 out goes to dead tmp; hf bf16 is what we need)
    ln512<1,false,false><<<ROWS/4, 256, 0, stream>>>(
        h, nullptr, nullptr, lnfw, lnfb, tmp, hf);

    // unembed: single-shot if the workspace can hold the full bf16 weight^T
    // (32000x512x2 = 32.77 MB + 2 MB hf), else 5 column chunks of 6400.
    if (ws_size >= (size_t)2097152 + (size_t)VOCAB_ * KDIM * 2) {
        wconvT<<<dim3(VOCAB_/32, KDIM/32, 1), 256, 0, stream>>>(
            unembW, VOCAB_, 0, z0, wun, KDIM, z0);
        gemm_bf16<128,128,false,true,false,false,false>
            <<<dim3(VOCAB_/128, 16, 1), 256, 0, stream>>>(
            hf, wun, unembB, outF, KDIM, KDIM, KDIM, VOCAB_,
            z0,z0,z0,z0,z0,z0, 1, 1.0f);
    } else {
        const int CH = 6400;
        for (int c = 0; c < 5; c++) {
            wconvT<<<dim3(CH/32, KDIM/32, 1), 256, 0, stream>>>(
                unembW, VOCAB_, c*CH, z0, wun, KDIM, z0);
            gemm_bf16<128,128,false,true,false,false,false>
                <<<dim3(CH/128, 16, 1), 256, 0, stream>>>(
                hf, wun, unembB + c*CH, outF + c*CH, KDIM, KDIM, KDIM, VOCAB_,
                z0,z0,z0,z0,z0,z0, 1, 1.0f);
        }
    }
}